// Round 1
// baseline (10474.850 us; speedup 1.0000x reference)
//
#include <hip/hip_runtime.h>
#include <hip/hip_bf16.h>

#define NB 32      // batch
#define NS 256     // seq len
#define NI 1024    // input size
#define NO 1024    // hidden size
#define NK 2048    // NI + NO
#define NC 4096    // 4 * NO
#define LN_EPS 1e-5f
#define SPIN_GUARD (1 << 17)   // ~27ms worst case; normal waits are <2us

typedef __attribute__((ext_vector_type(4))) float f32x4;
typedef __attribute__((ext_vector_type(4))) unsigned int u32x4;

__device__ __forceinline__ f32x4 mfma_bf16_16x16x32(u32x4 a, u32x4 b, f32x4 c) {
  asm volatile("v_mfma_f32_16x16x32_bf16 %0, %1, %2, %0" : "+v"(c) : "v"(a), "v"(b));
  return c;
}

__device__ __forceinline__ float sigf(float x) { return 1.0f / (1.0f + __expf(-x)); }
// tanh(x) = 1 - 2/(e^{2x}+1); exp overflow -> inf -> 1, underflow -> 0 -> -1. Both correct.
__device__ __forceinline__ float tanhfast(float x) {
  return 1.0f - 2.0f / (__expf(2.0f * x) + 1.0f);
}

// Bounded device-scope spin (monotonic counter, per-step => no reset races).
__device__ __forceinline__ void spin_until_ge(const unsigned int* p, unsigned int target) {
  for (int g = 0; g < SPIN_GUARD; ++g) {
    if (__hip_atomic_load(p, __ATOMIC_RELAXED, __HIP_MEMORY_SCOPE_AGENT) >= target) return;
    __builtin_amdgcn_s_sleep(2);
  }
}

// ---------------- setup kernels ----------------

// x fp32 [m][t][k] -> xfrag bf16 in MFMA A-fragment order:
// xfrag[((t*32 + kt)*2 + plane)*512 + l*8 + j] = x[m=plane*16+(l&15)][t][kt*32+(l>>4)*8+j]
// grid (256 t, 32 kt) x 128 thr.
__global__ void pack_x(const float* __restrict__ x, __hip_bfloat16* __restrict__ xfrag) {
  const int t = blockIdx.x, kt = blockIdx.y;
  const int tid = threadIdx.x;
  const int plane = tid >> 6, l = tid & 63, q = (l >> 4), ln = l & 15;
  const int m = plane * 16 + ln;
  const float* src = x + ((size_t)m * NS + t) * NI + kt * 32 + q * 8;
  float4 v0 = *(const float4*)src;
  float4 v1 = *(const float4*)(src + 4);
  __align__(16) __hip_bfloat16 tmp[8];
  tmp[0] = __float2bfloat16(v0.x); tmp[1] = __float2bfloat16(v0.y);
  tmp[2] = __float2bfloat16(v0.z); tmp[3] = __float2bfloat16(v0.w);
  tmp[4] = __float2bfloat16(v1.x); tmp[5] = __float2bfloat16(v1.y);
  tmp[6] = __float2bfloat16(v1.z); tmp[7] = __float2bfloat16(v1.w);
  *(u32x4*)(xfrag + (((size_t)t * 32 + kt) * 2 + plane) * 512 + l * 8) = *(const u32x4*)tmp;
}

// W fp32 [k=2048][n=4096] -> WF bf16 in MFMA-fragment order (round-3 verified).
__global__ void pack_wf(const float* __restrict__ W, __hip_bfloat16* __restrict__ WF) {
  const int blk = blockIdx.x;
  const int b = blk >> 6, kt = blk & 63;
  const int l = threadIdx.x, q = l >> 4, c = l & 15;
  const int n  = ((c >> 2) << 10) + b * 4 + (c & 3);
  const int k0 = kt * 32 + q * 8;
  __align__(16) __hip_bfloat16 tmp[8];
#pragma unroll
  for (int j = 0; j < 8; ++j)
    tmp[j] = __float2bfloat16(W[(size_t)(k0 + j) * NC + n]);
  *(u32x4*)(WF + ((size_t)(b * 64 + kt) * 64 + l) * 8) = *(const u32x4*)tmp;
}

// hfrag index for h[m][j] (A-fragment order, 2 planes of 16 rows):
__device__ __forceinline__ size_t hfrag_idx(int m, int j) {
  const int kt = j >> 5, q = (j >> 3) & 3, jj = j & 7;
  const int plane = m >> 4, l = q * 16 + (m & 15);
  return (((size_t)kt * 2 + plane) * 64 + l) * 8 + jj;
}

// init h (fragment order + fp32) and c from init_hx/init_cx (broadcast row 0)
__global__ void init_state(const float* __restrict__ hx0, const float* __restrict__ cx0,
                           __hip_bfloat16* __restrict__ hfrag, float* __restrict__ cst,
                           float* __restrict__ hf) {
  const int i = blockIdx.x * 256 + threadIdx.x;  // 32768 = NB*NO
  const int m = i >> 10, j = i & (NO - 1);
  const float hv = hx0[j];
  hfrag[hfrag_idx(m, j)] = __float2bfloat16(hv);
  hf[i]  = hv;
  cst[i] = cx0[j];
}

// ---------------- persistent cooperative kernel ----------------
// 256 blocks x 512 thr (1 block/CU). All 256 timesteps in one kernel.
// Per step:
//   GEMM phase (all blocks): block b computes comb[:, 16 interleaved cols].
//     Waves 0-3: x part (no dependency, runs ahead). Waves 4-7: h part,
//     spin on hcnt[t] (h of step t ready) first. W lives in registers.
//   Signal: ccnt[t][b>>3] += 1 after comb slice drained + wbL2.
//   Update phase (blocks 0-31): block m = batch row. Spin until all 32
//     group counters hit 8, then LN stats + gates + c/h update. c stays in
//     registers. Signal hcnt[t+1] += 1 after hfrag drained + wbL2.
__global__ __launch_bounds__(512)
void lstm_persistent(const __hip_bfloat16* __restrict__ xfrag,
                     __hip_bfloat16* __restrict__ hfrag,
                     const __hip_bfloat16* __restrict__ WF,
                     const float* __restrict__ bias,
                     const float* __restrict__ gamma,
                     const float* __restrict__ beta,
                     const float* __restrict__ cx0,
                     float* __restrict__ comb,
                     float* __restrict__ out,
                     unsigned int* __restrict__ ccnt,
                     unsigned int* __restrict__ hcnt) {
  __shared__ __align__(16) float xch[8 * 2 * 256];   // 16KB GEMM partials
  __shared__ __align__(16) float combL[NC];          // 16KB LN staging
  __shared__ float red[8][2];
  __shared__ float stat[2];

  const int b = blockIdx.x, tid = threadIdx.x;
  const int wv = tid >> 6, l = tid & 63;

  // --- loop-invariant: this block's W fragments in registers (64KB/block) ---
  u32x4 bb[8];
  {
    const __hip_bfloat16* bp = WF + ((size_t)(b * 64 + wv * 8) * 64 + l) * 8;
#pragma unroll
    for (int i = 0; i < 8; ++i) bb[i] = *(const u32x4*)(bp + (size_t)i * 512);
  }

  // epilogue mapping (constant): thread -> (row=tid>>4, c=tid&15)
  const int row = tid >> 4, c = tid & 15;
  const int p = row >> 4, rr = row & 15;
  const int idx = ((rr >> 2) * 16 + c) * 4 + (rr & 3);
  const int n = ((c >> 2) << 10) + b * 4 + (c & 3);
  const float bn = bias[n];

  // update-phase constants (used by blocks 0..31; loads valid for all)
  const int j0 = tid, j1 = tid + 512;
  const float gi0 = gamma[j0], gf0 = gamma[NO + j0], gg0 = gamma[2 * NO + j0], go0 = gamma[3 * NO + j0];
  const float gi1 = gamma[j1], gf1 = gamma[NO + j1], gg1 = gamma[2 * NO + j1], go1 = gamma[3 * NO + j1];
  const float bi0 = beta[j0], bf0 = beta[NO + j0], bg0 = beta[2 * NO + j0], bo0 = beta[3 * NO + j0];
  const float bi1 = beta[j1], bf1 = beta[NO + j1], bg1 = beta[2 * NO + j1], bo1 = beta[3 * NO + j1];
  float c0 = cx0[j0], c1 = cx0[j1];   // c-state in registers (row b)
  const int m = b;

  for (int t = 0; t < NS; ++t) {
    // ---------- GEMM phase ----------
    f32x4 acc0 = {0.f, 0.f, 0.f, 0.f}, acc1 = {0.f, 0.f, 0.f, 0.f};
    asm volatile("s_nop 1" ::);  // VALU-write(acc init) -> MFMA-read-C hazard
    if (wv < 4) {
      // x part: no dependency on h -- never waits.
      const __hip_bfloat16* ap = xfrag + ((size_t)t * 32 + wv * 8) * 1024 + l * 8;
#pragma unroll
      for (int i = 0; i < 8; ++i) {
        u32x4 a0 = *(const u32x4*)(ap + (size_t)i * 1024);
        u32x4 a1 = *(const u32x4*)(ap + (size_t)i * 1024 + 512);
        acc0 = mfma_bf16_16x16x32(a0, bb[i], acc0);
        acc1 = mfma_bf16_16x16x32(a1, bb[i], acc1);
      }
    } else {
      // h part: wait for h(t). t=0 h comes from init_state (kernel-boundary coherent).
      if (t > 0) spin_until_ge(hcnt + t, NB);
      __threadfence();  // acquire: invalidate stale h lines
      const __hip_bfloat16* ap = hfrag + ((size_t)(wv - 4) * 8) * 1024 + l * 8;
#pragma unroll
      for (int i = 0; i < 8; ++i) {
        u32x4 a0 = *(const u32x4*)(ap + (size_t)i * 1024);
        u32x4 a1 = *(const u32x4*)(ap + (size_t)i * 1024 + 512);
        acc0 = mfma_bf16_16x16x32(a0, bb[i], acc0);
        acc1 = mfma_bf16_16x16x32(a1, bb[i], acc1);
      }
    }
    asm volatile("s_nop 7\n\ts_nop 7" ::);  // MFMA-write -> VALU-read hazard

    *(f32x4*)(xch + (wv * 2 + 0) * 256 + l * 4) = acc0;
    *(f32x4*)(xch + (wv * 2 + 1) * 256 + l * 4) = acc1;
    __syncthreads();
    float v = bn;
#pragma unroll
    for (int w = 0; w < 8; ++w) v += xch[(w * 2 + p) * 256 + idx];
    comb[(size_t)row * NC + n] = v;
    __syncthreads();  // drain all comb stores to L2 (barrier implies vmcnt(0))
    if (tid == 0) {
      __threadfence();  // wbL2: publish comb slice device-wide
      __hip_atomic_fetch_add(ccnt + t * 32 + (b >> 3), 1u,
                             __ATOMIC_RELEASE, __HIP_MEMORY_SCOPE_AGENT);
    }

    // ---------- update phase (blocks 0..31, block = batch row) ----------
    if (b < NB) {
      if (tid < 64) {  // wave 0: each lane polls one of the 32 group counters
        spin_until_ge(ccnt + t * 32 + (tid & 31), 8);
        __threadfence();  // acquire: invalidate stale comb lines
      }
      __syncthreads();
      f32x4 cv0 = *(const f32x4*)(comb + (size_t)m * NC + tid * 8);
      f32x4 cv1 = *(const f32x4*)(comb + (size_t)m * NC + tid * 8 + 4);
      *(f32x4*)(combL + tid * 8)     = cv0;
      *(f32x4*)(combL + tid * 8 + 4) = cv1;
      float s  = cv0[0] + cv0[1] + cv0[2] + cv0[3] + cv1[0] + cv1[1] + cv1[2] + cv1[3];
      float ss = cv0[0] * cv0[0] + cv0[1] * cv0[1] + cv0[2] * cv0[2] + cv0[3] * cv0[3]
               + cv1[0] * cv1[0] + cv1[1] * cv1[1] + cv1[2] * cv1[2] + cv1[3] * cv1[3];
#pragma unroll
      for (int off = 1; off < 64; off <<= 1) {
        s  += __shfl_xor(s, off);
        ss += __shfl_xor(ss, off);
      }
      const int wid = tid >> 6;
      if ((tid & 63) == 0) { red[wid][0] = s; red[wid][1] = ss; }
      __syncthreads();
      if (tid == 0) {
        float s2 = 0.f, ss2 = 0.f;
#pragma unroll
        for (int i = 0; i < 8; ++i) { s2 += red[i][0]; ss2 += red[i][1]; }
        const float mean = s2 * (1.f / NC);
        const float var  = ss2 * (1.f / NC) - mean * mean;
        stat[0] = mean;
        stat[1] = rsqrtf(var + LN_EPS);
      }
      __syncthreads();
      const float mean = stat[0], rs = stat[1];
      const float iv0 = (combL[j0]           - mean) * rs * gi0 + bi0;
      const float fv0 = (combL[NO + j0]      - mean) * rs * gf0 + bf0;
      const float gv0 = (combL[2 * NO + j0]  - mean) * rs * gg0 + bg0;
      const float ov0 = (combL[3 * NO + j0]  - mean) * rs * go0 + bo0;
      const float iv1 = (combL[j1]           - mean) * rs * gi1 + bi1;
      const float fv1 = (combL[NO + j1]      - mean) * rs * gf1 + bf1;
      const float gv1 = (combL[2 * NO + j1]  - mean) * rs * gg1 + bg1;
      const float ov1 = (combL[3 * NO + j1]  - mean) * rs * go1 + bo1;
      const float cc0 = sigf(fv0) * c0 + sigf(iv0) * tanhfast(gv0);
      const float cc1 = sigf(fv1) * c1 + sigf(iv1) * tanhfast(gv1);
      const float hh0 = sigf(ov0) * cc0;
      const float hh1 = sigf(ov1) * cc1;
      c0 = cc0; c1 = cc1;
      out[((size_t)m * NS + t) * NO + j0] = hh0;
      out[((size_t)m * NS + t) * NO + j1] = hh1;
      hfrag[hfrag_idx(m, j0)] = __float2bfloat16(hh0);
      hfrag[hfrag_idx(m, j1)] = __float2bfloat16(hh1);
      __syncthreads();  // drain h stores
      if (tid == 0) {
        __threadfence();  // wbL2: publish h device-wide
        __hip_atomic_fetch_add(hcnt + (t + 1), 1u,
                               __ATOMIC_RELEASE, __HIP_MEMORY_SCOPE_AGENT);
      }
    }
  }
}

// ---------------- fallback (small ws): fp32 path ----------------

__launch_bounds__(256)
__global__ void step_gemm_f32(const float* __restrict__ x, const float* __restrict__ hf,
                              const float* __restrict__ W, const float* __restrict__ bias,
                              float* __restrict__ comb, int t) {
  const int blk = blockIdx.x;
  const int tid = threadIdx.x;
  const int n   = blk * 16 + (tid & 15);
  const int mlo = tid >> 4;
  float a0 = 0.f, a1 = 0.f;
  for (int k = 0; k < NI; ++k) {
    const float wv = W[(size_t)k * NC + n];
    a0 += x[((size_t)mlo * NS + t) * NI + k] * wv;
    a1 += x[((size_t)(mlo + 16) * NS + t) * NI + k] * wv;
  }
  for (int k = 0; k < NO; ++k) {
    const float wv = W[(size_t)(NI + k) * NC + n];
    a0 += hf[mlo * NO + k] * wv;
    a1 += hf[(mlo + 16) * NO + k] * wv;
  }
  comb[(size_t)mlo * NC + n] = a0 + bias[n];
  comb[(size_t)(mlo + 16) * NC + n] = a1 + bias[n];
}

__global__ __launch_bounds__(1024)
void step_update_row_f32(const float* __restrict__ comb,
                         const float* __restrict__ gamma,
                         const float* __restrict__ beta,
                         float* __restrict__ cst,
                         float* __restrict__ out,
                         float* __restrict__ hf,
                         int t) {
  __shared__ __align__(16) float combL[NC];
  __shared__ float red[16][2];
  __shared__ float stat[2];
  const int m = blockIdx.x, tid = threadIdx.x;
  f32x4 cv = *(const f32x4*)(comb + (size_t)m * NC + tid * 4);
  *(f32x4*)(combL + tid * 4) = cv;
  float s  = cv[0] + cv[1] + cv[2] + cv[3];
  float ss = cv[0] * cv[0] + cv[1] * cv[1] + cv[2] * cv[2] + cv[3] * cv[3];
#pragma unroll
  for (int off = 1; off < 64; off <<= 1) {
    s  += __shfl_xor(s, off);
    ss += __shfl_xor(ss, off);
  }
  const int wid = tid >> 6;
  if ((tid & 63) == 0) { red[wid][0] = s; red[wid][1] = ss; }
  __syncthreads();
  if (tid == 0) {
    float s2 = 0.f, ss2 = 0.f;
    for (int i = 0; i < 16; ++i) { s2 += red[i][0]; ss2 += red[i][1]; }
    const float mean = s2 * (1.f / NC);
    const float var  = ss2 * (1.f / NC) - mean * mean;
    stat[0] = mean;
    stat[1] = rsqrtf(var + LN_EPS);
  }
  __syncthreads();
  const float mean = stat[0], rs = stat[1];
  const int j = tid;
  const float iv = (combL[j]          - mean) * rs * gamma[j]          + beta[j];
  const float fv = (combL[NO + j]     - mean) * rs * gamma[NO + j]     + beta[NO + j];
  const float gv = (combL[2 * NO + j] - mean) * rs * gamma[2 * NO + j] + beta[2 * NO + j];
  const float ov = (combL[3 * NO + j] - mean) * rs * gamma[3 * NO + j] + beta[3 * NO + j];
  const float cold = cst[(size_t)m * NO + j];
  const float cc = sigf(fv) * cold + sigf(iv) * tanhfast(gv);
  const float hh = sigf(ov) * cc;
  cst[(size_t)m * NO + j] = cc;
  out[((size_t)m * NS + t) * NO + j] = hh;
  hf[(size_t)m * NO + j] = hh;
}

// ---------------- launch ----------------

extern "C" void kernel_launch(void* const* d_in, const int* in_sizes, int n_in,
                              void* d_out, int out_size, void* d_ws, size_t ws_size,
                              hipStream_t stream) {
  (void)in_sizes; (void)n_in; (void)out_size;
  const float* x     = (const float*)d_in[0];
  const float* W     = (const float*)d_in[1];
  const float* bias  = (const float*)d_in[2];
  const float* gamma = (const float*)d_in[3];
  const float* beta  = (const float*)d_in[4];
  const float* hx0   = (const float*)d_in[5];
  const float* cx0   = (const float*)d_in[6];
  float* outp = (float*)d_out;

  char* ws = (char*)d_ws;
  size_t off = 0;
  auto alloc = [&](size_t bytes) -> char* {
    off = (off + 255) & ~(size_t)255;
    char* p = ws + off;
    off += bytes;
    return p;
  };
  // small buffers first (fallback needs only these)
  float* comb          = (float*)alloc((size_t)NB * NC * 4);        // 512KB
  float* cst           = (float*)alloc((size_t)NB * NO * 4);        // 128KB
  float* hf            = (float*)alloc((size_t)NB * NO * 4);        // 128KB
  __hip_bfloat16* hfrag = (__hip_bfloat16*)alloc((size_t)NB * NO * 2);  // 64KB
  unsigned int* ccnt   = (unsigned int*)alloc((size_t)NS * 32 * 4);     // 32KB
  unsigned int* hcnt   = (unsigned int*)alloc((size_t)(NS + 1) * 4);    // 1KB
  // big buffers
  __hip_bfloat16* xfrag = (__hip_bfloat16*)alloc((size_t)NB * NS * NI * 2);  // 16.8MB
  __hip_bfloat16* WF    = (__hip_bfloat16*)alloc((size_t)NK * NC * 2);       // 16.8MB
  const bool big = (ws_size >= off);   // ws_size constant -> same path every call

  hipLaunchKernelGGL(init_state, dim3((NB * NO) / 256), dim3(256), 0, stream,
                     hx0, cx0, hfrag, cst, hf);
  if (big) {
    hipMemsetAsync(ccnt, 0, (size_t)NS * 32 * 4, stream);
    hipMemsetAsync(hcnt, 0, (size_t)(NS + 1) * 4, stream);
    hipLaunchKernelGGL(pack_x, dim3(NS, 32), dim3(128), 0, stream, x, xfrag);
    hipLaunchKernelGGL(pack_wf, dim3(256 * 64), dim3(64), 0, stream, W, WF);
    void* args[] = {(void*)&xfrag, (void*)&hfrag, (void*)&WF, (void*)&bias,
                    (void*)&gamma, (void*)&beta, (void*)&cx0, (void*)&comb,
                    (void*)&outp, (void*)&ccnt, (void*)&hcnt};
    hipLaunchCooperativeKernel((void*)lstm_persistent, dim3(256), dim3(512),
                               args, 0, stream);
  } else {
    for (int t = 0; t < NS; ++t) {
      hipLaunchKernelGGL(step_gemm_f32, dim3(256), dim3(256), 0, stream,
                         x, hf, W, bias, comb, t);
      hipLaunchKernelGGL(step_update_row_f32, dim3(NB), dim3(1024), 0, stream,
                         comb, gamma, beta, cst, outp, hf, t);
    }
  }
}

// Round 3
// 9515.788 us; speedup vs baseline: 1.1008x; 1.1008x over previous
//
#include <hip/hip_runtime.h>
#include <hip/hip_bf16.h>

#define NB 32      // batch
#define NS 256     // seq len
#define NI 1024    // input size
#define NO 1024    // hidden size
#define NK 2048    // NI + NO
#define NC 4096    // 4 * NO
#define LN_EPS 1e-5f
#define SPIN_GUARD (1 << 18)

typedef __attribute__((ext_vector_type(4))) float f32x4;
typedef __attribute__((ext_vector_type(4))) unsigned int u32x4;

__device__ __forceinline__ f32x4 mfma_bf16_16x16x32(u32x4 a, u32x4 b, f32x4 c) {
  asm volatile("v_mfma_f32_16x16x32_bf16 %0, %1, %2, %0" : "+v"(c) : "v"(a), "v"(b));
  return c;
}

__device__ __forceinline__ float sigf(float x) { return 1.0f / (1.0f + __expf(-x)); }
__device__ __forceinline__ float tanhfast(float x) {
  return 1.0f - 2.0f / (__expf(2.0f * x) + 1.0f);
}

// ---- MALL-coherent primitives ----
// Loads: sc0 sc1 = bypass L1+L2, read the device-coherent point directly.
// Writes/flags: no-return atomics with sc1 -> RMW performed AT the coherent
// point; vmcnt retires on its ack. flag-visible => data-visible, rigorously.
__device__ __forceinline__ unsigned int load_coh_u32(const void* p) {
  unsigned int v;
  asm volatile("global_load_dword %0, %1, off sc0 sc1\n\ts_waitcnt vmcnt(0)"
               : "=&v"(v) : "v"(p));
  return v;
}
__device__ __forceinline__ float load_coh_f32(const void* p) {
  float v;
  asm volatile("global_load_dword %0, %1, off sc0 sc1\n\ts_waitcnt vmcnt(0)"
               : "=&v"(v) : "v"(p));
  return v;
}
__device__ __forceinline__ void atomic_swap_coh_u32(void* p, unsigned int v) {
  asm volatile("global_atomic_swap %0, %1, off sc1" :: "v"(p), "v"(v) : "memory");
}
__device__ __forceinline__ void atomic_add_coh_u32(void* p, unsigned int v) {
  asm volatile("global_atomic_add %0, %1, off sc1" :: "v"(p), "v"(v) : "memory");
}
__device__ __forceinline__ void atomic_add_coh_f32(void* p, float v) {
  asm volatile("global_atomic_add_f32 %0, %1, off sc1" :: "v"(p), "v"(v) : "memory");
}
// 8x 16B coherent loads, one waitcnt (self-contained: outputs valid after stmt)
#define COH_LOAD8(d, a0,a1,a2,a3,a4,a5,a6,a7)                          \
  asm volatile(                                                         \
    "global_load_dwordx4 %0, %8, off sc0 sc1\n\t"                      \
    "global_load_dwordx4 %1, %9, off sc0 sc1\n\t"                      \
    "global_load_dwordx4 %2, %10, off sc0 sc1\n\t"                     \
    "global_load_dwordx4 %3, %11, off sc0 sc1\n\t"                     \
    "global_load_dwordx4 %4, %12, off sc0 sc1\n\t"                     \
    "global_load_dwordx4 %5, %13, off sc0 sc1\n\t"                     \
    "global_load_dwordx4 %6, %14, off sc0 sc1\n\t"                     \
    "global_load_dwordx4 %7, %15, off sc0 sc1\n\t"                     \
    "s_waitcnt vmcnt(0)"                                                \
    : "=&v"(d[0]), "=&v"(d[1]), "=&v"(d[2]), "=&v"(d[3]),               \
      "=&v"(d[4]), "=&v"(d[5]), "=&v"(d[6]), "=&v"(d[7])                \
    : "v"(a0), "v"(a1), "v"(a2), "v"(a3), "v"(a4), "v"(a5), "v"(a6), "v"(a7))

__device__ __forceinline__ void poll_coh_ge(const unsigned int* p, unsigned int target) {
  for (int g = 0; g < SPIN_GUARD; ++g) {
    if (load_coh_u32(p) >= target) return;
    __builtin_amdgcn_s_sleep(2);
  }
}

// ---------------- setup kernels ----------------

// x fp32 [m][t][k] -> xfrag bf16 in MFMA A-fragment order.
__global__ void pack_x(const float* __restrict__ x, __hip_bfloat16* __restrict__ xfrag) {
  const int t = blockIdx.x, kt = blockIdx.y;
  const int tid = threadIdx.x;
  const int plane = tid >> 6, l = tid & 63, q = (l >> 4), ln = l & 15;
  const int m = plane * 16 + ln;
  const float* src = x + ((size_t)m * NS + t) * NI + kt * 32 + q * 8;
  float4 v0 = *(const float4*)src;
  float4 v1 = *(const float4*)(src + 4);
  __align__(16) __hip_bfloat16 tmp[8];
  tmp[0] = __float2bfloat16(v0.x); tmp[1] = __float2bfloat16(v0.y);
  tmp[2] = __float2bfloat16(v0.z); tmp[3] = __float2bfloat16(v0.w);
  tmp[4] = __float2bfloat16(v1.x); tmp[5] = __float2bfloat16(v1.y);
  tmp[6] = __float2bfloat16(v1.z); tmp[7] = __float2bfloat16(v1.w);
  *(u32x4*)(xfrag + (((size_t)t * 32 + kt) * 2 + plane) * 512 + l * 8) = *(const u32x4*)tmp;
}

// W fp32 [k=2048][n=4096] -> WF bf16 in MFMA-fragment order.
__global__ void pack_wf(const float* __restrict__ W, __hip_bfloat16* __restrict__ WF) {
  const int blk = blockIdx.x;
  const int b = blk >> 6, kt = blk & 63;
  const int l = threadIdx.x, q = l >> 4, c = l & 15;
  const int n  = ((c >> 2) << 10) + b * 4 + (c & 3);
  const int k0 = kt * 32 + q * 8;
  __align__(16) __hip_bfloat16 tmp[8];
#pragma unroll
  for (int j = 0; j < 8; ++j)
    tmp[j] = __float2bfloat16(W[(size_t)(k0 + j) * NC + n]);
  *(u32x4*)(WF + ((size_t)(b * 64 + kt) * 64 + l) * 8) = *(const u32x4*)tmp;
}

// hfrag index for h[m][j] (A-fragment order, 2 planes of 16 rows):
__device__ __forceinline__ size_t hfrag_idx(int m, int j) {
  const int kt = j >> 5, q = (j >> 3) & 3, jj = j & 7;
  const int plane = m >> 4, l = q * 16 + (m & 15);
  return (((size_t)kt * 2 + plane) * 64 + l) * 8 + jj;
}

// init for fp32 fallback path only
__global__ void init_state(const float* __restrict__ hx0, const float* __restrict__ cx0,
                           float* __restrict__ cst, float* __restrict__ hf) {
  const int i = blockIdx.x * 256 + threadIdx.x;
  const int j = i & (NO - 1);
  hf[i]  = hx0[j];
  cst[i] = cx0[j];
}

// ---------------- persistent cooperative kernel ----------------
// 256 blocks x 512 thr. Block b owns output cols n(c)=(c>>2)*1024+b*4+(c&3),
// i.e. ALL FOUR gate pre-activations for hidden units j=4b..4b+3 -> gates are
// block-local. Per step:
//   waves 1-3: x-GEMM (never wait). waves 4-7: wait hcnt[t]=256, bypass-load
//   h, h-GEMM. All: LDS-reduce partials, per-row LN partial stats via
//   sc1 fp32 atomics into srow[t][row]; vmcnt-drain + barrier; tid0 bumps
//   scnt[t] (sc1 atomic). wave 0: poll scnt[t]=256, bypass-read stats,
//   LN+gates+c (c in regs), publish h slice via sc1 atomic-swaps, vmcnt(0),
//   bump hcnt[t+1].
// All cross-block data flows through MALL-level atomics (sc1) and bypass
// loads; x/W stay normally cached (read-only).
__global__ __launch_bounds__(512)
void lstm_persistent(const __hip_bfloat16* __restrict__ xfrag,
                     __hip_bfloat16* __restrict__ hfrag,
                     const __hip_bfloat16* __restrict__ WF,
                     const float* __restrict__ bias,
                     const float* __restrict__ gamma,
                     const float* __restrict__ beta,
                     const float* __restrict__ hx0,
                     const float* __restrict__ cx0,
                     float* __restrict__ out,
                     float* __restrict__ srow,           // [NS][32][2]
                     unsigned int* __restrict__ scnt,    // [NS]
                     unsigned int* __restrict__ hcnt) {  // [NS+1]
  __shared__ __align__(16) float xch[8 * 2 * 256];   // 16KB GEMM partials
  __shared__ __align__(16) float combB[32 * 16];     // 2KB block-local comb
  __shared__ int hgo;                                 // LDS relay of hcnt

  const int b = blockIdx.x, tid = threadIdx.x;
  const int wv = tid >> 6, l = tid & 63;

  // K-tile assignment: wv0 none; wv1-3 x-ktiles (11/11/10); wv4-7 h-ktiles (8)
  int kt0, nkt;
  if (wv == 0)      { kt0 = 0; nkt = 0; }
  else if (wv < 4)  { kt0 = (wv - 1) * 11; nkt = (wv == 3) ? 10 : 11; }
  else              { kt0 = 32 + (wv - 4) * 8; nkt = 8; }

  u32x4 bb[11];
  {
    const __hip_bfloat16* bp = WF + ((size_t)(b * 64 + kt0) * 64 + l) * 8;
#pragma unroll
    for (int i = 0; i < 11; ++i)
      if (i < nkt) bb[i] = *(const u32x4*)(bp + (size_t)i * 512);
  }

  // epilogue mapping: thread -> (row=tid>>4, c=tid&15)
  const int row = tid >> 4, c = tid & 15;
  const int p = row >> 4, rr = row & 15;
  const int idx = ((rr >> 2) * 16 + c) * 4 + (rr & 3);
  const int n = ((c >> 2) << 10) + b * 4 + (c & 3);
  const float bn = bias[n];

  // wave0 gate-lane state: lane l -> (m=l>>1, half=l&1), owns j0=4b+2*half, j0+1
  const int gm = l >> 1, gh = l & 1;
  const int j0 = b * 4 + 2 * gh;
  float ga[4][2], be[4][2];
  float c0 = 0.f, c1 = 0.f;
  if (wv == 0) {
#pragma unroll
    for (int g = 0; g < 4; ++g) {
      ga[g][0] = gamma[g * NO + j0]; ga[g][1] = gamma[g * NO + j0 + 1];
      be[g][0] = beta[g * NO + j0];  be[g][1] = beta[g * NO + j0 + 1];
    }
    c0 = cx0[j0]; c1 = cx0[j0 + 1];
  }
  if (tid == 0) hgo = 0;
  __syncthreads();

  for (int t = 0; t < NS; ++t) {
    // ---------- GEMM phase ----------
    f32x4 acc0 = {0.f, 0.f, 0.f, 0.f}, acc1 = {0.f, 0.f, 0.f, 0.f};
    asm volatile("s_nop 1" ::);  // VALU-write(acc init) -> MFMA-read-C hazard
    if (wv >= 1 && wv < 4) {
      // x part: no dependency on h -- never waits; normal cached loads.
      const __hip_bfloat16* ap = xfrag + ((size_t)t * 32 + kt0) * 1024 + l * 8;
#pragma unroll
      for (int i = 0; i < 11; ++i)
        if (i < nkt) {
          u32x4 a0 = *(const u32x4*)(ap + (size_t)i * 1024);
          u32x4 a1 = *(const u32x4*)(ap + (size_t)i * 1024 + 512);
          acc0 = mfma_bf16_16x16x32(a0, bb[i], acc0);
          acc1 = mfma_bf16_16x16x32(a1, bb[i], acc1);
        }
    } else if (wv >= 4) {
      u32x4 ha[8], hb[8];
      if (t == 0) {
        // h(0) = broadcast of hx0 row: build fragments locally, no sync.
        const int q = l >> 4;
#pragma unroll
        for (int i = 0; i < 8; ++i) {
          const int k0 = ((wv - 4) * 8 + i) * 32 + q * 8;
          float4 v0 = *(const float4*)(hx0 + k0);
          float4 v1 = *(const float4*)(hx0 + k0 + 4);
          __align__(16) __hip_bfloat16 tmp[8];
          tmp[0] = __float2bfloat16(v0.x); tmp[1] = __float2bfloat16(v0.y);
          tmp[2] = __float2bfloat16(v0.z); tmp[3] = __float2bfloat16(v0.w);
          tmp[4] = __float2bfloat16(v1.x); tmp[5] = __float2bfloat16(v1.y);
          tmp[6] = __float2bfloat16(v1.z); tmp[7] = __float2bfloat16(v1.w);
          ha[i] = *(const u32x4*)tmp;
          hb[i] = ha[i];
        }
      } else {
        // wait h(t): wave4 polls global, relays via LDS; waves 5-7 spin LDS.
        if (wv == 4) {
          poll_coh_ge(hcnt + t, 256u);
          if (l == 0)
            __hip_atomic_store(&hgo, t, __ATOMIC_RELEASE, __HIP_MEMORY_SCOPE_WORKGROUP);
        } else {
          for (int g = 0; g < SPIN_GUARD; ++g) {
            if (__hip_atomic_load(&hgo, __ATOMIC_ACQUIRE, __HIP_MEMORY_SCOPE_WORKGROUP) >= t)
              break;
            __builtin_amdgcn_s_sleep(1);
          }
        }
        __builtin_amdgcn_sched_barrier(0);
        const __hip_bfloat16* ap = hfrag + ((size_t)(wv - 4) * 8) * 1024 + l * 8;
        COH_LOAD8(ha, ap + (size_t)0 * 1024, ap + (size_t)1 * 1024,
                      ap + (size_t)2 * 1024, ap + (size_t)3 * 1024,
                      ap + (size_t)4 * 1024, ap + (size_t)5 * 1024,
                      ap + (size_t)6 * 1024, ap + (size_t)7 * 1024);
        COH_LOAD8(hb, ap + (size_t)0 * 1024 + 512, ap + (size_t)1 * 1024 + 512,
                      ap + (size_t)2 * 1024 + 512, ap + (size_t)3 * 1024 + 512,
                      ap + (size_t)4 * 1024 + 512, ap + (size_t)5 * 1024 + 512,
                      ap + (size_t)6 * 1024 + 512, ap + (size_t)7 * 1024 + 512);
        __builtin_amdgcn_sched_barrier(0);
      }
#pragma unroll
      for (int i = 0; i < 8; ++i) {
        acc0 = mfma_bf16_16x16x32(ha[i], bb[i], acc0);
        acc1 = mfma_bf16_16x16x32(hb[i], bb[i], acc1);
      }
    }
    asm volatile("s_nop 7\n\ts_nop 7" ::);  // MFMA-write -> VALU-read hazard

    if (wv >= 1) {
      *(f32x4*)(xch + (wv * 2 + 0) * 256 + l * 4) = acc0;
      *(f32x4*)(xch + (wv * 2 + 1) * 256 + l * 4) = acc1;
    }
    __syncthreads();

    // ---------- epilogue: comb to LDS + LN partial stats ----------
    float v = bn;
#pragma unroll
    for (int w = 1; w < 8; ++w) v += xch[(w * 2 + p) * 256 + idx];
    combB[row * 16 + c] = v;
    float s = v, ss = v * v;
#pragma unroll
    for (int off = 1; off < 16; off <<= 1) {
      s  += __shfl_xor(s, off);
      ss += __shfl_xor(ss, off);
    }
    if (c == 0) {
      atomic_add_coh_f32(srow + ((size_t)t * 32 + row) * 2 + 0, s);
      atomic_add_coh_f32(srow + ((size_t)t * 32 + row) * 2 + 1, ss);
    }
    // drain asm atomics explicitly (don't rely on barrier lowering to count
    // inline-asm VMEM ops), then barrier => all 512 threads' adds at MALL.
    asm volatile("s_waitcnt vmcnt(0)" ::: "memory");
    __syncthreads();
    if (tid == 0) atomic_add_coh_u32(scnt + t, 1u);

    // ---------- gate phase (wave 0 only) ----------
    if (wv == 0) {
      poll_coh_ge(scnt + t, 256u);
      __builtin_amdgcn_sched_barrier(0);
      const float sv  = load_coh_f32(srow + ((size_t)t * 32 + gm) * 2 + 0);
      const float ssv = load_coh_f32(srow + ((size_t)t * 32 + gm) * 2 + 1);
      const float mean = sv * (1.f / NC);
      const float var  = ssv * (1.f / NC) - mean * mean;
      const float rs = rsqrtf(var + LN_EPS);
      const int cb = 2 * gh;
      float pre[4][2];
#pragma unroll
      for (int g = 0; g < 4; ++g) {
        pre[g][0] = (combB[gm * 16 + g * 4 + cb]     - mean) * rs * ga[g][0] + be[g][0];
        pre[g][1] = (combB[gm * 16 + g * 4 + cb + 1] - mean) * rs * ga[g][1] + be[g][1];
      }
      const float cc0 = sigf(pre[1][0]) * c0 + sigf(pre[0][0]) * tanhfast(pre[2][0]);
      const float cc1 = sigf(pre[1][1]) * c1 + sigf(pre[0][1]) * tanhfast(pre[2][1]);
      const float hh0 = sigf(pre[3][0]) * cc0;
      const float hh1 = sigf(pre[3][1]) * cc1;
      c0 = cc0; c1 = cc1;
      float2 o2; o2.x = hh0; o2.y = hh1;
      *(float2*)(out + ((size_t)gm * NS + t) * NO + j0) = o2;
      __hip_bfloat16 hb0 = __float2bfloat16(hh0), hb1 = __float2bfloat16(hh1);
      unsigned int hp = (unsigned int)*(unsigned short*)&hb0 |
                        ((unsigned int)*(unsigned short*)&hb1 << 16);
      // publish h THROUGH the coherent point: swap-without-return executes the
      // store at MALL; vmcnt(0) waits for the MALL ack; then raise the flag.
      atomic_swap_coh_u32((void*)(hfrag + hfrag_idx(gm, j0)), hp);
      asm volatile("s_waitcnt vmcnt(0)" ::: "memory");
      if (l == 0) atomic_add_coh_u32(hcnt + t + 1, 1u);
    }
  }
}

// ---------------- fallback (small ws): fp32 path ----------------

__launch_bounds__(256)
__global__ void step_gemm_f32(const float* __restrict__ x, const float* __restrict__ hf,
                              const float* __restrict__ W, const float* __restrict__ bias,
                              float* __restrict__ comb, int t) {
  const int blk = blockIdx.x;
  const int tid = threadIdx.x;
  const int n   = blk * 16 + (tid & 15);
  const int mlo = tid >> 4;
  float a0 = 0.f, a1 = 0.f;
  for (int k = 0; k < NI; ++k) {
    const float wv = W[(size_t)k * NC + n];
    a0 += x[((size_t)mlo * NS + t) * NI + k] * wv;
    a1 += x[((size_t)(mlo + 16) * NS + t) * NI + k] * wv;
  }
  for (int k = 0; k < NO; ++k) {
    const float wv = W[(size_t)(NI + k) * NC + n];
    a0 += hf[mlo * NO + k] * wv;
    a1 += hf[(mlo + 16) * NO + k] * wv;
  }
  comb[(size_t)mlo * NC + n] = a0 + bias[n];
  comb[(size_t)(mlo + 16) * NC + n] = a1 + bias[n];
}

__global__ __launch_bounds__(1024)
void step_update_row_f32(const float* __restrict__ comb,
                         const float* __restrict__ gamma,
                         const float* __restrict__ beta,
                         float* __restrict__ cst,
                         float* __restrict__ out,
                         float* __restrict__ hf,
                         int t) {
  __shared__ __align__(16) float combL[NC];
  __shared__ float red[16][2];
  __shared__ float stat[2];
  const int m = blockIdx.x, tid = threadIdx.x;
  f32x4 cv = *(const f32x4*)(comb + (size_t)m * NC + tid * 4);
  *(f32x4*)(combL + tid * 4) = cv;
  float s  = cv[0] + cv[1] + cv[2] + cv[3];
  float ss = cv[0] * cv[0] + cv[1] * cv[1] + cv[2] * cv[2] + cv[3] * cv[3];
#pragma unroll
  for (int off = 1; off < 64; off <<= 1) {
    s  += __shfl_xor(s, off);
    ss += __shfl_xor(ss, off);
  }
  const int wid = tid >> 6;
  if ((tid & 63) == 0) { red[wid][0] = s; red[wid][1] = ss; }
  __syncthreads();
  if (tid == 0) {
    float s2 = 0.f, ss2 = 0.f;
    for (int i = 0; i < 16; ++i) { s2 += red[i][0]; ss2 += red[i][1]; }
    const float mean = s2 * (1.f / NC);
    const float var  = ss2 * (1.f / NC) - mean * mean;
    stat[0] = mean;
    stat[1] = rsqrtf(var + LN_EPS);
  }
  __syncthreads();
  const float mean = stat[0], rs = stat[1];
  const int j = tid;
  const float iv = (combL[j]          - mean) * rs * gamma[j]          + beta[j];
  const float fv = (combL[NO + j]     - mean) * rs * gamma[NO + j]     + beta[NO + j];
  const float gv = (combL[2 * NO + j] - mean) * rs * gamma[2 * NO + j] + beta[2 * NO + j];
  const float ov = (combL[3 * NO + j] - mean) * rs * gamma[3 * NO + j] + beta[3 * NO + j];
  const float cold = cst[(size_t)m * NO + j];
  const float cc = sigf(fv) * cold + sigf(iv) * tanhfast(gv);
  const float hh = sigf(ov) * cc;
  cst[(size_t)m * NO + j] = cc;
  out[((size_t)m * NS + t) * NO + j] = hh;
  hf[(size_t)m * NO + j] = hh;
}

// ---------------- launch ----------------

extern "C" void kernel_launch(void* const* d_in, const int* in_sizes, int n_in,
                              void* d_out, int out_size, void* d_ws, size_t ws_size,
                              hipStream_t stream) {
  (void)in_sizes; (void)n_in; (void)out_size;
  const float* x     = (const float*)d_in[0];
  const float* W     = (const float*)d_in[1];
  const float* bias  = (const float*)d_in[2];
  const float* gamma = (const float*)d_in[3];
  const float* beta  = (const float*)d_in[4];
  const float* hx0   = (const float*)d_in[5];
  const float* cx0   = (const float*)d_in[6];
  float* outp = (float*)d_out;

  char* ws = (char*)d_ws;
  size_t off = 0;
  auto alloc = [&](size_t bytes) -> char* {
    off = (off + 255) & ~(size_t)255;
    char* p = ws + off;
    off += bytes;
    return p;
  };
  // small buffers first (fallback needs only comb/cst/hf)
  float* comb          = (float*)alloc((size_t)NB * NC * 4);        // 512KB
  float* cst           = (float*)alloc((size_t)NB * NO * 4);        // 128KB
  float* hf            = (float*)alloc((size_t)NB * NO * 4);        // 128KB
  __hip_bfloat16* hfrag = (__hip_bfloat16*)alloc((size_t)NB * NO * 2);  // 64KB
  float* srow          = (float*)alloc((size_t)NS * 32 * 2 * 4);        // 64KB
  unsigned int* scnt   = (unsigned int*)alloc((size_t)NS * 4);          // 1KB
  unsigned int* hcnt   = (unsigned int*)alloc((size_t)(NS + 1) * 4);    // 1KB
  // big buffers
  __hip_bfloat16* xfrag = (__hip_bfloat16*)alloc((size_t)NB * NS * NI * 2);  // 16.8MB
  __hip_bfloat16* WF    = (__hip_bfloat16*)alloc((size_t)NK * NC * 2);       // 16.8MB
  const bool big = (ws_size >= off);   // ws_size constant -> same path every call

  if (big) {
    hipMemsetAsync(srow, 0, (size_t)NS * 32 * 2 * 4, stream);
    hipMemsetAsync(scnt, 0, (size_t)NS * 4, stream);
    hipMemsetAsync(hcnt, 0, (size_t)(NS + 1) * 4, stream);
    hipLaunchKernelGGL(pack_x, dim3(NS, 32), dim3(128), 0, stream, x, xfrag);
    hipLaunchKernelGGL(pack_wf, dim3(256 * 64), dim3(64), 0, stream, W, WF);
    void* args[] = {(void*)&xfrag, (void*)&hfrag, (void*)&WF, (void*)&bias,
                    (void*)&gamma, (void*)&beta, (void*)&hx0, (void*)&cx0,
                    (void*)&outp, (void*)&srow, (void*)&scnt, (void*)&hcnt};
    hipLaunchCooperativeKernel((void*)lstm_persistent, dim3(256), dim3(512),
                               args, 0, stream);
  } else {
    hipLaunchKernelGGL(init_state, dim3((NB * NO) / 256), dim3(256), 0, stream,
                       hx0, cx0, cst, hf);
    for (int t = 0; t < NS; ++t) {
      hipLaunchKernelGGL(step_gemm_f32, dim3(256), dim3(256), 0, stream,
                         x, hf, W, bias, comb, t);
      hipLaunchKernelGGL(step_update_row_f32, dim3(NB), dim3(1024), 0, stream,
                         comb, gamma, beta, cst, outp, hf, t);
    }
  }
}

// Round 4
// 6896.062 us; speedup vs baseline: 1.5190x; 1.3799x over previous
//
#include <hip/hip_runtime.h>
#include <hip/hip_bf16.h>

#define NB 32      // batch
#define NS 256     // seq len
#define NI 1024    // input size
#define NO 1024    // hidden size
#define NK 2048    // NI + NO
#define NC 4096    // 4 * NO
#define LN_EPS 1e-5f
#define SPIN_GUARD (1 << 18)

// padded layouts (anti cache-line-serialization at the coherent point)
#define SROW_STRIDE 16   // floats per (t,row) slot = 64B; s at +0, ss at +8 (32B)
#define CNT_STRIDE  32   // u32 per step slot = 128B

typedef __attribute__((ext_vector_type(4))) float f32x4;
typedef __attribute__((ext_vector_type(4))) unsigned int u32x4;

__device__ __forceinline__ f32x4 mfma_bf16_16x16x32(u32x4 a, u32x4 b, f32x4 c) {
  asm volatile("v_mfma_f32_16x16x32_bf16 %0, %1, %2, %0" : "+v"(c) : "v"(a), "v"(b));
  return c;
}

__device__ __forceinline__ float sigf(float x) { return 1.0f / (1.0f + __expf(-x)); }
__device__ __forceinline__ float tanhfast(float x) {
  return 1.0f - 2.0f / (__expf(2.0f * x) + 1.0f);
}

// ---- MALL-coherent primitives ----
// Loads: sc0 sc1 = bypass L1+L2, read the device-coherent point directly.
// Writes/flags: no-return atomics with sc1 -> RMW performed AT the coherent
// point; vmcnt retires on its ack. flag-visible => data-visible, rigorously.
__device__ __forceinline__ unsigned int load_coh_u32(const void* p) {
  unsigned int v;
  asm volatile("global_load_dword %0, %1, off sc0 sc1\n\ts_waitcnt vmcnt(0)"
               : "=&v"(v) : "v"(p));
  return v;
}
__device__ __forceinline__ float load_coh_f32(const void* p) {
  float v;
  asm volatile("global_load_dword %0, %1, off sc0 sc1\n\ts_waitcnt vmcnt(0)"
               : "=&v"(v) : "v"(p));
  return v;
}
__device__ __forceinline__ void atomic_swap_coh_u32(void* p, unsigned int v) {
  asm volatile("global_atomic_swap %0, %1, off sc1" :: "v"(p), "v"(v) : "memory");
}
__device__ __forceinline__ void atomic_add_coh_u32(void* p, unsigned int v) {
  asm volatile("global_atomic_add %0, %1, off sc1" :: "v"(p), "v"(v) : "memory");
}
__device__ __forceinline__ void atomic_add_coh_f32(void* p, float v) {
  asm volatile("global_atomic_add_f32 %0, %1, off sc1" :: "v"(p), "v"(v) : "memory");
}
// 8x 16B coherent loads, one waitcnt (self-contained: outputs valid after stmt)
#define COH_LOAD8(d, a0,a1,a2,a3,a4,a5,a6,a7)                          \
  asm volatile(                                                         \
    "global_load_dwordx4 %0, %8, off sc0 sc1\n\t"                      \
    "global_load_dwordx4 %1, %9, off sc0 sc1\n\t"                      \
    "global_load_dwordx4 %2, %10, off sc0 sc1\n\t"                     \
    "global_load_dwordx4 %3, %11, off sc0 sc1\n\t"                     \
    "global_load_dwordx4 %4, %12, off sc0 sc1\n\t"                     \
    "global_load_dwordx4 %5, %13, off sc0 sc1\n\t"                     \
    "global_load_dwordx4 %6, %14, off sc0 sc1\n\t"                     \
    "global_load_dwordx4 %7, %15, off sc0 sc1\n\t"                     \
    "s_waitcnt vmcnt(0)"                                                \
    : "=&v"(d[0]), "=&v"(d[1]), "=&v"(d[2]), "=&v"(d[3]),               \
      "=&v"(d[4]), "=&v"(d[5]), "=&v"(d[6]), "=&v"(d[7])                \
    : "v"(a0), "v"(a1), "v"(a2), "v"(a3), "v"(a4), "v"(a5), "v"(a6), "v"(a7))

__device__ __forceinline__ void poll_coh_ge(const unsigned int* p, unsigned int target) {
  for (int g = 0; g < SPIN_GUARD; ++g) {
    if (load_coh_u32(p) >= target) return;
    __builtin_amdgcn_s_sleep(8);   // ~512cy backoff: keep poll pressure off the flag line
  }
}

// ---------------- setup kernels ----------------

// x fp32 [m][t][k] -> xfrag bf16 in MFMA A-fragment order.
__global__ void pack_x(const float* __restrict__ x, __hip_bfloat16* __restrict__ xfrag) {
  const int t = blockIdx.x, kt = blockIdx.y;
  const int tid = threadIdx.x;
  const int plane = tid >> 6, l = tid & 63, q = (l >> 4), ln = l & 15;
  const int m = plane * 16 + ln;
  const float* src = x + ((size_t)m * NS + t) * NI + kt * 32 + q * 8;
  float4 v0 = *(const float4*)src;
  float4 v1 = *(const float4*)(src + 4);
  __align__(16) __hip_bfloat16 tmp[8];
  tmp[0] = __float2bfloat16(v0.x); tmp[1] = __float2bfloat16(v0.y);
  tmp[2] = __float2bfloat16(v0.z); tmp[3] = __float2bfloat16(v0.w);
  tmp[4] = __float2bfloat16(v1.x); tmp[5] = __float2bfloat16(v1.y);
  tmp[6] = __float2bfloat16(v1.z); tmp[7] = __float2bfloat16(v1.w);
  *(u32x4*)(xfrag + (((size_t)t * 32 + kt) * 2 + plane) * 512 + l * 8) = *(const u32x4*)tmp;
}

// W fp32 [k=2048][n=4096] -> WF bf16 in MFMA-fragment order.
__global__ void pack_wf(const float* __restrict__ W, __hip_bfloat16* __restrict__ WF) {
  const int blk = blockIdx.x;
  const int b = blk >> 6, kt = blk & 63;
  const int l = threadIdx.x, q = l >> 4, c = l & 15;
  const int n  = ((c >> 2) << 10) + b * 4 + (c & 3);
  const int k0 = kt * 32 + q * 8;
  __align__(16) __hip_bfloat16 tmp[8];
#pragma unroll
  for (int j = 0; j < 8; ++j)
    tmp[j] = __float2bfloat16(W[(size_t)(k0 + j) * NC + n]);
  *(u32x4*)(WF + ((size_t)(b * 64 + kt) * 64 + l) * 8) = *(const u32x4*)tmp;
}

// hfrag index for h[m][j] (A-fragment order, 2 planes of 16 rows):
__device__ __forceinline__ size_t hfrag_idx(int m, int j) {
  const int kt = j >> 5, q = (j >> 3) & 3, jj = j & 7;
  const int plane = m >> 4, l = q * 16 + (m & 15);
  return (((size_t)kt * 2 + plane) * 64 + l) * 8 + jj;
}

// init for fp32 fallback path only
__global__ void init_state(const float* __restrict__ hx0, const float* __restrict__ cx0,
                           float* __restrict__ cst, float* __restrict__ hf) {
  const int i = blockIdx.x * 256 + threadIdx.x;
  const int j = i & (NO - 1);
  hf[i]  = hx0[j];
  cst[i] = cx0[j];
}

// ---------------- persistent cooperative kernel ----------------
// Identical protocol to the round-3 (passing) kernel; ONLY the addressing of
// srow/scnt/hcnt changed: each hot counter now owns its own 64B/128B slot so
// the 16K stat-RMWs per step spread across ~16 cache lines instead of 1-2.
__global__ __launch_bounds__(512)
void lstm_persistent(const __hip_bfloat16* __restrict__ xfrag,
                     __hip_bfloat16* __restrict__ hfrag,
                     const __hip_bfloat16* __restrict__ WF,
                     const float* __restrict__ bias,
                     const float* __restrict__ gamma,
                     const float* __restrict__ beta,
                     const float* __restrict__ hx0,
                     const float* __restrict__ cx0,
                     float* __restrict__ out,
                     float* __restrict__ srow,           // [NS][32][SROW_STRIDE]
                     unsigned int* __restrict__ scnt,    // [NS][CNT_STRIDE]
                     unsigned int* __restrict__ hcnt) {  // [NS+1][CNT_STRIDE]
  __shared__ __align__(16) float xch[8 * 2 * 256];   // 16KB GEMM partials
  __shared__ __align__(16) float combB[32 * 16];     // 2KB block-local comb
  __shared__ int hgo;                                 // LDS relay of hcnt

  const int b = blockIdx.x, tid = threadIdx.x;
  const int wv = tid >> 6, l = tid & 63;

  // K-tile assignment: wv0 none; wv1-3 x-ktiles (11/11/10); wv4-7 h-ktiles (8)
  int kt0, nkt;
  if (wv == 0)      { kt0 = 0; nkt = 0; }
  else if (wv < 4)  { kt0 = (wv - 1) * 11; nkt = (wv == 3) ? 10 : 11; }
  else              { kt0 = 32 + (wv - 4) * 8; nkt = 8; }

  u32x4 bb[11];
  {
    const __hip_bfloat16* bp = WF + ((size_t)(b * 64 + kt0) * 64 + l) * 8;
#pragma unroll
    for (int i = 0; i < 11; ++i)
      if (i < nkt) bb[i] = *(const u32x4*)(bp + (size_t)i * 512);
  }

  // epilogue mapping: thread -> (row=tid>>4, c=tid&15)
  const int row = tid >> 4, c = tid & 15;
  const int p = row >> 4, rr = row & 15;
  const int idx = ((rr >> 2) * 16 + c) * 4 + (rr & 3);
  const int n = ((c >> 2) << 10) + b * 4 + (c & 3);
  const float bn = bias[n];

  // wave0 gate-lane state: lane l -> (m=l>>1, half=l&1), owns j0=4b+2*half, j0+1
  const int gm = l >> 1, gh = l & 1;
  const int j0 = b * 4 + 2 * gh;
  float ga[4][2], be[4][2];
  float c0 = 0.f, c1 = 0.f;
  if (wv == 0) {
#pragma unroll
    for (int g = 0; g < 4; ++g) {
      ga[g][0] = gamma[g * NO + j0]; ga[g][1] = gamma[g * NO + j0 + 1];
      be[g][0] = beta[g * NO + j0];  be[g][1] = beta[g * NO + j0 + 1];
    }
    c0 = cx0[j0]; c1 = cx0[j0 + 1];
  }
  if (tid == 0) hgo = 0;
  __syncthreads();

  for (int t = 0; t < NS; ++t) {
    // ---------- GEMM phase ----------
    f32x4 acc0 = {0.f, 0.f, 0.f, 0.f}, acc1 = {0.f, 0.f, 0.f, 0.f};
    asm volatile("s_nop 1" ::);  // VALU-write(acc init) -> MFMA-read-C hazard
    if (wv >= 1 && wv < 4) {
      // x part: no dependency on h -- never waits; normal cached loads.
      const __hip_bfloat16* ap = xfrag + ((size_t)t * 32 + kt0) * 1024 + l * 8;
#pragma unroll
      for (int i = 0; i < 11; ++i)
        if (i < nkt) {
          u32x4 a0 = *(const u32x4*)(ap + (size_t)i * 1024);
          u32x4 a1 = *(const u32x4*)(ap + (size_t)i * 1024 + 512);
          acc0 = mfma_bf16_16x16x32(a0, bb[i], acc0);
          acc1 = mfma_bf16_16x16x32(a1, bb[i], acc1);
        }
    } else if (wv >= 4) {
      u32x4 ha[8], hb[8];
      if (t == 0) {
        // h(0) = broadcast of hx0 row: build fragments locally, no sync.
        const int q = l >> 4;
#pragma unroll
        for (int i = 0; i < 8; ++i) {
          const int k0 = ((wv - 4) * 8 + i) * 32 + q * 8;
          float4 v0 = *(const float4*)(hx0 + k0);
          float4 v1 = *(const float4*)(hx0 + k0 + 4);
          __align__(16) __hip_bfloat16 tmp[8];
          tmp[0] = __float2bfloat16(v0.x); tmp[1] = __float2bfloat16(v0.y);
          tmp[2] = __float2bfloat16(v0.z); tmp[3] = __float2bfloat16(v0.w);
          tmp[4] = __float2bfloat16(v1.x); tmp[5] = __float2bfloat16(v1.y);
          tmp[6] = __float2bfloat16(v1.z); tmp[7] = __float2bfloat16(v1.w);
          ha[i] = *(const u32x4*)tmp;
          hb[i] = ha[i];
        }
      } else {
        // wait h(t): wave4 polls global, relays via LDS; waves 5-7 spin LDS.
        if (wv == 4) {
          poll_coh_ge(hcnt + (size_t)t * CNT_STRIDE, 256u);
          if (l == 0)
            __hip_atomic_store(&hgo, t, __ATOMIC_RELEASE, __HIP_MEMORY_SCOPE_WORKGROUP);
        } else {
          for (int g = 0; g < SPIN_GUARD; ++g) {
            if (__hip_atomic_load(&hgo, __ATOMIC_ACQUIRE, __HIP_MEMORY_SCOPE_WORKGROUP) >= t)
              break;
            __builtin_amdgcn_s_sleep(1);
          }
        }
        __builtin_amdgcn_sched_barrier(0);
        const __hip_bfloat16* ap = hfrag + ((size_t)(wv - 4) * 8) * 1024 + l * 8;
        COH_LOAD8(ha, ap + (size_t)0 * 1024, ap + (size_t)1 * 1024,
                      ap + (size_t)2 * 1024, ap + (size_t)3 * 1024,
                      ap + (size_t)4 * 1024, ap + (size_t)5 * 1024,
                      ap + (size_t)6 * 1024, ap + (size_t)7 * 1024);
        COH_LOAD8(hb, ap + (size_t)0 * 1024 + 512, ap + (size_t)1 * 1024 + 512,
                      ap + (size_t)2 * 1024 + 512, ap + (size_t)3 * 1024 + 512,
                      ap + (size_t)4 * 1024 + 512, ap + (size_t)5 * 1024 + 512,
                      ap + (size_t)6 * 1024 + 512, ap + (size_t)7 * 1024 + 512);
        __builtin_amdgcn_sched_barrier(0);
      }
#pragma unroll
      for (int i = 0; i < 8; ++i) {
        acc0 = mfma_bf16_16x16x32(ha[i], bb[i], acc0);
        acc1 = mfma_bf16_16x16x32(hb[i], bb[i], acc1);
      }
    }
    asm volatile("s_nop 7\n\ts_nop 7" ::);  // MFMA-write -> VALU-read hazard

    if (wv >= 1) {
      *(f32x4*)(xch + (wv * 2 + 0) * 256 + l * 4) = acc0;
      *(f32x4*)(xch + (wv * 2 + 1) * 256 + l * 4) = acc1;
    }
    __syncthreads();

    // ---------- epilogue: comb to LDS + LN partial stats ----------
    float v = bn;
#pragma unroll
    for (int w = 1; w < 8; ++w) v += xch[(w * 2 + p) * 256 + idx];
    combB[row * 16 + c] = v;
    float s = v, ss = v * v;
#pragma unroll
    for (int off = 1; off < 16; off <<= 1) {
      s  += __shfl_xor(s, off);
      ss += __shfl_xor(ss, off);
    }
    if (c == 0) {
      float* slot = srow + ((size_t)t * 32 + row) * SROW_STRIDE;
      atomic_add_coh_f32(slot + 0, s);
      atomic_add_coh_f32(slot + 8, ss);   // +32B: own sector
    }
    // drain asm atomics explicitly, then barrier => all 512 threads' adds at MALL.
    asm volatile("s_waitcnt vmcnt(0)" ::: "memory");
    __syncthreads();
    if (tid == 0) atomic_add_coh_u32(scnt + (size_t)t * CNT_STRIDE, 1u);

    // ---------- gate phase (wave 0 only) ----------
    if (wv == 0) {
      poll_coh_ge(scnt + (size_t)t * CNT_STRIDE, 256u);
      __builtin_amdgcn_sched_barrier(0);
      const float* slot = srow + ((size_t)t * 32 + gm) * SROW_STRIDE;
      const float sv  = load_coh_f32(slot + 0);
      const float ssv = load_coh_f32(slot + 8);
      const float mean = sv * (1.f / NC);
      const float var  = ssv * (1.f / NC) - mean * mean;
      const float rs = rsqrtf(var + LN_EPS);
      const int cb = 2 * gh;
      float pre[4][2];
#pragma unroll
      for (int g = 0; g < 4; ++g) {
        pre[g][0] = (combB[gm * 16 + g * 4 + cb]     - mean) * rs * ga[g][0] + be[g][0];
        pre[g][1] = (combB[gm * 16 + g * 4 + cb + 1] - mean) * rs * ga[g][1] + be[g][1];
      }
      const float cc0 = sigf(pre[1][0]) * c0 + sigf(pre[0][0]) * tanhfast(pre[2][0]);
      const float cc1 = sigf(pre[1][1]) * c1 + sigf(pre[0][1]) * tanhfast(pre[2][1]);
      const float hh0 = sigf(pre[3][0]) * cc0;
      const float hh1 = sigf(pre[3][1]) * cc1;
      c0 = cc0; c1 = cc1;
      float2 o2; o2.x = hh0; o2.y = hh1;
      *(float2*)(out + ((size_t)gm * NS + t) * NO + j0) = o2;
      __hip_bfloat16 hb0 = __float2bfloat16(hh0), hb1 = __float2bfloat16(hh1);
      unsigned int hp = (unsigned int)*(unsigned short*)&hb0 |
                        ((unsigned int)*(unsigned short*)&hb1 << 16);
      // publish h THROUGH the coherent point: swap-without-return executes the
      // store at MALL; vmcnt(0) waits for the MALL ack; then raise the flag.
      atomic_swap_coh_u32((void*)(hfrag + hfrag_idx(gm, j0)), hp);
      asm volatile("s_waitcnt vmcnt(0)" ::: "memory");
      if (l == 0) atomic_add_coh_u32(hcnt + (size_t)(t + 1) * CNT_STRIDE, 1u);
    }
  }
}

// ---------------- fallback (small ws): fp32 path ----------------

__launch_bounds__(256)
__global__ void step_gemm_f32(const float* __restrict__ x, const float* __restrict__ hf,
                              const float* __restrict__ W, const float* __restrict__ bias,
                              float* __restrict__ comb, int t) {
  const int blk = blockIdx.x;
  const int tid = threadIdx.x;
  const int n   = blk * 16 + (tid & 15);
  const int mlo = tid >> 4;
  float a0 = 0.f, a1 = 0.f;
  for (int k = 0; k < NI; ++k) {
    const float wv = W[(size_t)k * NC + n];
    a0 += x[((size_t)mlo * NS + t) * NI + k] * wv;
    a1 += x[((size_t)(mlo + 16) * NS + t) * NI + k] * wv;
  }
  for (int k = 0; k < NO; ++k) {
    const float wv = W[(size_t)(NI + k) * NC + n];
    a0 += hf[mlo * NO + k] * wv;
    a1 += hf[(mlo + 16) * NO + k] * wv;
  }
  comb[(size_t)mlo * NC + n] = a0 + bias[n];
  comb[(size_t)(mlo + 16) * NC + n] = a1 + bias[n];
}

__global__ __launch_bounds__(1024)
void step_update_row_f32(const float* __restrict__ comb,
                         const float* __restrict__ gamma,
                         const float* __restrict__ beta,
                         float* __restrict__ cst,
                         float* __restrict__ out,
                         float* __restrict__ hf,
                         int t) {
  __shared__ __align__(16) float combL[NC];
  __shared__ float red[16][2];
  __shared__ float stat[2];
  const int m = blockIdx.x, tid = threadIdx.x;
  f32x4 cv = *(const f32x4*)(comb + (size_t)m * NC + tid * 4);
  *(f32x4*)(combL + tid * 4) = cv;
  float s  = cv[0] + cv[1] + cv[2] + cv[3];
  float ss = cv[0] * cv[0] + cv[1] * cv[1] + cv[2] * cv[2] + cv[3] * cv[3];
#pragma unroll
  for (int off = 1; off < 64; off <<= 1) {
    s  += __shfl_xor(s, off);
    ss += __shfl_xor(ss, off);
  }
  const int wid = tid >> 6;
  if ((tid & 63) == 0) { red[wid][0] = s; red[wid][1] = ss; }
  __syncthreads();
  if (tid == 0) {
    float s2 = 0.f, ss2 = 0.f;
    for (int i = 0; i < 16; ++i) { s2 += red[i][0]; ss2 += red[i][1]; }
    const float mean = s2 * (1.f / NC);
    const float var  = ss2 * (1.f / NC) - mean * mean;
    stat[0] = mean;
    stat[1] = rsqrtf(var + LN_EPS);
  }
  __syncthreads();
  const float mean = stat[0], rs = stat[1];
  const int j = tid;
  const float iv = (combL[j]          - mean) * rs * gamma[j]          + beta[j];
  const float fv = (combL[NO + j]     - mean) * rs * gamma[NO + j]     + beta[NO + j];
  const float gv = (combL[2 * NO + j] - mean) * rs * gamma[2 * NO + j] + beta[2 * NO + j];
  const float ov = (combL[3 * NO + j] - mean) * rs * gamma[3 * NO + j] + beta[3 * NO + j];
  const float cold = cst[(size_t)m * NO + j];
  const float cc = sigf(fv) * cold + sigf(iv) * tanhfast(gv);
  const float hh = sigf(ov) * cc;
  cst[(size_t)m * NO + j] = cc;
  out[((size_t)m * NS + t) * NO + j] = hh;
  hf[(size_t)m * NO + j] = hh;
}

// ---------------- launch ----------------

extern "C" void kernel_launch(void* const* d_in, const int* in_sizes, int n_in,
                              void* d_out, int out_size, void* d_ws, size_t ws_size,
                              hipStream_t stream) {
  (void)in_sizes; (void)n_in; (void)out_size;
  const float* x     = (const float*)d_in[0];
  const float* W     = (const float*)d_in[1];
  const float* bias  = (const float*)d_in[2];
  const float* gamma = (const float*)d_in[3];
  const float* beta  = (const float*)d_in[4];
  const float* hx0   = (const float*)d_in[5];
  const float* cx0   = (const float*)d_in[6];
  float* outp = (float*)d_out;

  char* ws = (char*)d_ws;
  size_t off = 0;
  auto alloc = [&](size_t bytes) -> char* {
    off = (off + 255) & ~(size_t)255;
    char* p = ws + off;
    off += bytes;
    return p;
  };
  // small buffers first (fallback needs only comb/cst/hf)
  float* comb          = (float*)alloc((size_t)NB * NC * 4);        // 512KB
  float* cst           = (float*)alloc((size_t)NB * NO * 4);        // 128KB
  float* hf            = (float*)alloc((size_t)NB * NO * 4);        // 128KB
  __hip_bfloat16* hfrag = (__hip_bfloat16*)alloc((size_t)NB * NO * 2);  // 64KB
  unsigned int* scnt   = (unsigned int*)alloc((size_t)NS * CNT_STRIDE * 4);       // 32KB
  unsigned int* hcnt   = (unsigned int*)alloc((size_t)(NS + 1) * CNT_STRIDE * 4); // 33KB
  // big buffers
  __hip_bfloat16* xfrag = (__hip_bfloat16*)alloc((size_t)NB * NS * NI * 2);  // 16.8MB
  __hip_bfloat16* WF    = (__hip_bfloat16*)alloc((size_t)NK * NC * 2);       // 16.8MB
  const bool big = (ws_size >= off);   // ws_size constant -> same path every call

  // big path: srow (padded LN-stat slots, NS*32*16 floats = 512KB) aliases comb
  float* srow = comb;

  if (big) {
    hipMemsetAsync(srow, 0, (size_t)NS * 32 * SROW_STRIDE * 4, stream);
    hipMemsetAsync(scnt, 0, (size_t)NS * CNT_STRIDE * 4, stream);
    hipMemsetAsync(hcnt, 0, (size_t)(NS + 1) * CNT_STRIDE * 4, stream);
    hipLaunchKernelGGL(pack_x, dim3(NS, 32), dim3(128), 0, stream, x, xfrag);
    hipLaunchKernelGGL(pack_wf, dim3(256 * 64), dim3(64), 0, stream, W, WF);
    void* args[] = {(void*)&xfrag, (void*)&hfrag, (void*)&WF, (void*)&bias,
                    (void*)&gamma, (void*)&beta, (void*)&hx0, (void*)&cx0,
                    (void*)&outp, (void*)&srow, (void*)&scnt, (void*)&hcnt};
    hipLaunchCooperativeKernel((void*)lstm_persistent, dim3(256), dim3(512),
                               args, 0, stream);
  } else {
    hipLaunchKernelGGL(init_state, dim3((NB * NO) / 256), dim3(256), 0, stream,
                       hx0, cx0, cst, hf);
    for (int t = 0; t < NS; ++t) {
      hipLaunchKernelGGL(step_gemm_f32, dim3(256), dim3(256), 0, stream,
                         x, hf, W, bias, comb, t);
      hipLaunchKernelGGL(step_update_row_f32, dim3(NB), dim3(1024), 0, stream,
                         comb, gamma, beta, cst, outp, hf, t);
    }
  }
}

// Round 5
// 2497.148 us; speedup vs baseline: 4.1947x; 2.7616x over previous
//
#include <hip/hip_runtime.h>
#include <hip/hip_bf16.h>

#define NB 32      // batch
#define NS 256     // seq len
#define NI 1024    // input size
#define NO 1024    // hidden size
#define NK 2048    // NI + NO
#define NC 4096    // 4 * NO
#define LN_EPS 1e-5f

typedef __attribute__((ext_vector_type(4))) float f32x4;
typedef __attribute__((ext_vector_type(4))) unsigned int u32x4;

__device__ __forceinline__ f32x4 mfma_bf16_16x16x32(u32x4 a, u32x4 b, f32x4 c) {
  asm volatile("v_mfma_f32_16x16x32_bf16 %0, %1, %2, %0" : "+v"(c) : "v"(a), "v"(b));
  return c;
}

__device__ __forceinline__ float sigf(float x) { return 1.0f / (1.0f + __expf(-x)); }
// tanh(x) = 1 - 2/(e^{2x}+1); exp overflow -> inf -> 1, underflow -> 0 -> -1. Both correct.
__device__ __forceinline__ float tanhfast(float x) {
  return 1.0f - 2.0f / (__expf(2.0f * x) + 1.0f);
}

// ---------------- setup kernels (round-0 proven) ----------------

// x fp32 [m][t][k] -> xfrag bf16 in MFMA A-fragment order:
// xfrag[((t*32 + kt)*2 + plane)*512 + l*8 + j] = x[m=plane*16+(l&15)][t][kt*32+(l>>4)*8+j]
__global__ void pack_x(const float* __restrict__ x, __hip_bfloat16* __restrict__ xfrag) {
  const int t = blockIdx.x, kt = blockIdx.y;
  const int tid = threadIdx.x;
  const int plane = tid >> 6, l = tid & 63, q = (l >> 4), ln = l & 15;
  const int m = plane * 16 + ln;
  const float* src = x + ((size_t)m * NS + t) * NI + kt * 32 + q * 8;
  float4 v0 = *(const float4*)src;
  float4 v1 = *(const float4*)(src + 4);
  __align__(16) __hip_bfloat16 tmp[8];
  tmp[0] = __float2bfloat16(v0.x); tmp[1] = __float2bfloat16(v0.y);
  tmp[2] = __float2bfloat16(v0.z); tmp[3] = __float2bfloat16(v0.w);
  tmp[4] = __float2bfloat16(v1.x); tmp[5] = __float2bfloat16(v1.y);
  tmp[6] = __float2bfloat16(v1.z); tmp[7] = __float2bfloat16(v1.w);
  *(u32x4*)(xfrag + (((size_t)t * 32 + kt) * 2 + plane) * 512 + l * 8) = *(const u32x4*)tmp;
}

// W fp32 [k=2048][n=4096] -> WF bf16 in MFMA-fragment order.
__global__ void pack_wf(const float* __restrict__ W, __hip_bfloat16* __restrict__ WF) {
  const int blk = blockIdx.x;
  const int b = blk >> 6, kt = blk & 63;
  const int l = threadIdx.x, q = l >> 4, c = l & 15;
  const int n  = ((c >> 2) << 10) + b * 4 + (c & 3);
  const int k0 = kt * 32 + q * 8;
  __align__(16) __hip_bfloat16 tmp[8];
#pragma unroll
  for (int j = 0; j < 8; ++j)
    tmp[j] = __float2bfloat16(W[(size_t)(k0 + j) * NC + n]);
  *(u32x4*)(WF + ((size_t)(b * 64 + kt) * 64 + l) * 8) = *(const u32x4*)tmp;
}

// hfrag index for h[m][j] (A-fragment order, 2 planes of 16 rows):
__device__ __forceinline__ size_t hfrag_idx(int m, int j) {
  const int kt = j >> 5, q = (j >> 3) & 3, jj = j & 7;
  const int plane = m >> 4, l = q * 16 + (m & 15);
  return (((size_t)kt * 2 + plane) * 64 + l) * 8 + jj;
}

// init h (fragment order + fp32) and c from init_hx/init_cx (broadcast row 0)
__global__ void init_state(const float* __restrict__ hx0, const float* __restrict__ cx0,
                           __hip_bfloat16* __restrict__ hfrag, float* __restrict__ cst,
                           float* __restrict__ hf) {
  const int i = blockIdx.x * 256 + threadIdx.x;  // 32768 = NB*NO
  const int m = i >> 10, j = i & (NO - 1);
  const float hv = hx0[j];
  hfrag[hfrag_idx(m, j)] = __float2bfloat16(hv);
  hf[i]  = hv;
  cst[i] = cx0[j];
}

// ---------------- hoisted x-GEMM (no serial dependency) ----------------
// One dispatch computes xa[t][b][tid] = bias[n] + x_t @ Wx for ALL 256 steps.
// Block b owns its 16 interleaved cols; all 8 waves split the 32 x k-tiles
// (4 each). Output stored bf16 in exactly the layout step_gemm_h's epilogue
// thread (row=tid>>4, c=tid&15) consumes: one coalesced 2B load per thread.
__global__ __launch_bounds__(512)
void xgemm_all(const __hip_bfloat16* __restrict__ xfrag,
               const __hip_bfloat16* __restrict__ WF,
               const float* __restrict__ bias,
               __hip_bfloat16* __restrict__ xa) {
  __shared__ __align__(16) float xch[8 * 2 * 256];   // 16KB partials
  const int b = blockIdx.x, tid = threadIdx.x;
  const int wv = tid >> 6, l = tid & 63;
  const int kt0 = wv * 4;                 // x k-tiles 0..31, 4 per wave
  u32x4 bb[4];
  {
    const __hip_bfloat16* bp = WF + ((size_t)(b * 64 + kt0) * 64 + l) * 8;
#pragma unroll
    for (int i = 0; i < 4; ++i) bb[i] = *(const u32x4*)(bp + (size_t)i * 512);
  }
  const int row = tid >> 4, c = tid & 15;
  const int p = row >> 4, rr = row & 15;
  const int idx = ((rr >> 2) * 16 + c) * 4 + (rr & 3);
  const int n = ((c >> 2) << 10) + b * 4 + (c & 3);
  const float bn = bias[n];

  for (int t = 0; t < NS; ++t) {
    f32x4 acc0 = {0.f, 0.f, 0.f, 0.f}, acc1 = {0.f, 0.f, 0.f, 0.f};
    asm volatile("s_nop 1" ::);  // VALU-write(acc init) -> MFMA-read-C hazard
    const __hip_bfloat16* ap = xfrag + ((size_t)t * 32 + kt0) * 1024 + l * 8;
#pragma unroll
    for (int i = 0; i < 4; ++i) {
      u32x4 a0 = *(const u32x4*)(ap + (size_t)i * 1024);        // plane 0
      u32x4 a1 = *(const u32x4*)(ap + (size_t)i * 1024 + 512);  // plane 1
      acc0 = mfma_bf16_16x16x32(a0, bb[i], acc0);
      acc1 = mfma_bf16_16x16x32(a1, bb[i], acc1);
    }
    asm volatile("s_nop 7\n\ts_nop 7" ::);  // MFMA-write -> VALU-read hazard
    *(f32x4*)(xch + (wv * 2 + 0) * 256 + l * 4) = acc0;
    *(f32x4*)(xch + (wv * 2 + 1) * 256 + l * 4) = acc1;
    __syncthreads();
    float v = bn;
#pragma unroll
    for (int w = 0; w < 8; ++w) v += xch[(w * 2 + p) * 256 + idx];
    xa[((size_t)t * 256 + b) * 512 + tid] = __float2bfloat16(v);
    __syncthreads();   // xch reuse next t
  }
}

// ---------------- per-step kernel A (tier1): h-GEMM only, K=1024 ----------------
// Same structure as the proven step_gemm_mfma but all 8 waves cover the 32
// h k-tiles (4 each); epilogue seeds from precomputed xa (bias folded in).
__global__ __launch_bounds__(512)
void step_gemm_h(const __hip_bfloat16* __restrict__ hfrag,
                 const __hip_bfloat16* __restrict__ WF,
                 const __hip_bfloat16* __restrict__ xa,
                 float* __restrict__ comb, int t) {
  __shared__ __align__(16) float xch[8 * 2 * 256];   // 16KB
  const int b = blockIdx.x, tid = threadIdx.x;
  const int wv = tid >> 6, l = tid & 63;
  const int kt0 = wv * 4;   // h k-tiles 0..31, 4 per wave
  const __hip_bfloat16* ap = hfrag + (size_t)kt0 * 1024 + l * 8;
  const __hip_bfloat16* bp = WF + ((size_t)(b * 64 + 32 + kt0) * 64 + l) * 8;

  f32x4 acc0 = {0.f, 0.f, 0.f, 0.f}, acc1 = {0.f, 0.f, 0.f, 0.f};
  asm volatile("s_nop 1" ::);  // VALU-write(acc init) -> MFMA-read-C hazard
#pragma unroll
  for (int i = 0; i < 4; ++i) {
    u32x4 a0 = *(const u32x4*)(ap + (size_t)i * 1024);        // plane 0
    u32x4 a1 = *(const u32x4*)(ap + (size_t)i * 1024 + 512);  // plane 1
    u32x4 bbv = *(const u32x4*)(bp + (size_t)i * 512);
    acc0 = mfma_bf16_16x16x32(a0, bbv, acc0);
    acc1 = mfma_bf16_16x16x32(a1, bbv, acc1);
  }
  asm volatile("s_nop 7\n\ts_nop 7" ::);  // MFMA-write -> VALU-read hazard

  *(f32x4*)(xch + (wv * 2 + 0) * 256 + l * 4) = acc0;
  *(f32x4*)(xch + (wv * 2 + 1) * 256 + l * 4) = acc1;
  __syncthreads();

  const int row = tid >> 4, c = tid & 15;
  const int p = row >> 4, rr = row & 15;
  const int idx = ((rr >> 2) * 16 + c) * 4 + (rr & 3);
  const int n = ((c >> 2) << 10) + b * 4 + (c & 3);
  float v = __bfloat162float(xa[((size_t)t * 256 + b) * 512 + tid]);
#pragma unroll
  for (int w = 0; w < 8; ++w) v += xch[(w * 2 + p) * 256 + idx];
  comb[(size_t)row * NC + n] = v;
}

// ---------------- per-step kernel A (tier2 = exact round-0): K=2048 ----------------
__global__ __launch_bounds__(512)
void step_gemm_mfma(const __hip_bfloat16* __restrict__ xfrag,
                    const __hip_bfloat16* __restrict__ hfrag,
                    const __hip_bfloat16* __restrict__ WF,
                    const float* __restrict__ bias,
                    float* __restrict__ comb, int t) {
  __shared__ __align__(16) float xch[8 * 2 * 256];   // 16KB
  const int b = blockIdx.x, tid = threadIdx.x;
  const int wv = tid >> 6, l = tid & 63;

  const __hip_bfloat16* ap = (wv < 4)
      ? xfrag + ((size_t)t * 32 + wv * 8) * 1024 + l * 8
      : hfrag + ((size_t)(wv - 4) * 8) * 1024 + l * 8;
  const __hip_bfloat16* bp = WF + ((size_t)(b * 64 + wv * 8) * 64 + l) * 8;

  f32x4 acc0 = {0.f, 0.f, 0.f, 0.f}, acc1 = {0.f, 0.f, 0.f, 0.f};
  asm volatile("s_nop 1" ::);
#pragma unroll
  for (int i = 0; i < 8; ++i) {
    u32x4 a0 = *(const u32x4*)(ap + (size_t)i * 1024);
    u32x4 a1 = *(const u32x4*)(ap + (size_t)i * 1024 + 512);
    u32x4 bb = *(const u32x4*)(bp + (size_t)i * 512);
    acc0 = mfma_bf16_16x16x32(a0, bb, acc0);
    acc1 = mfma_bf16_16x16x32(a1, bb, acc1);
  }
  asm volatile("s_nop 7\n\ts_nop 7" ::);

  *(f32x4*)(xch + (wv * 2 + 0) * 256 + l * 4) = acc0;
  *(f32x4*)(xch + (wv * 2 + 1) * 256 + l * 4) = acc1;
  __syncthreads();

  const int row = tid >> 4, c = tid & 15;
  const int p = row >> 4, rr = row & 15;
  const int idx = ((rr >> 2) * 16 + c) * 4 + (rr & 3);
  const int n = ((c >> 2) << 10) + b * 4 + (c & 3);
  float v = bias[n];
#pragma unroll
  for (int w = 0; w < 8; ++w) v += xch[(w * 2 + p) * 256 + idx];
  comb[(size_t)row * NC + n] = v;
}

// ---------------- per-step kernel B (exact round-0): LN + gates + state ----------------
__global__ __launch_bounds__(1024)
void step_update_row(const float* __restrict__ comb,
                     const float* __restrict__ gamma,
                     const float* __restrict__ beta,
                     float* __restrict__ cst,
                     float* __restrict__ out,
                     __hip_bfloat16* __restrict__ hfrag,
                     int t) {
  __shared__ __align__(16) float combL[NC];
  __shared__ float red[16][2];
  __shared__ float stat[2];
  const int m = blockIdx.x, tid = threadIdx.x;

  f32x4 cv = *(const f32x4*)(comb + (size_t)m * NC + tid * 4);
  *(f32x4*)(combL + tid * 4) = cv;
  float s  = cv[0] + cv[1] + cv[2] + cv[3];
  float ss = cv[0] * cv[0] + cv[1] * cv[1] + cv[2] * cv[2] + cv[3] * cv[3];
#pragma unroll
  for (int off = 1; off < 64; off <<= 1) {
    s  += __shfl_xor(s, off);
    ss += __shfl_xor(ss, off);
  }
  const int wid = tid >> 6;
  if ((tid & 63) == 0) { red[wid][0] = s; red[wid][1] = ss; }
  __syncthreads();
  if (tid == 0) {
    float s2 = 0.f, ss2 = 0.f;
#pragma unroll
    for (int i = 0; i < 16; ++i) { s2 += red[i][0]; ss2 += red[i][1]; }
    const float mean = s2 * (1.f / NC);
    const float var  = ss2 * (1.f / NC) - mean * mean;
    stat[0] = mean;
    stat[1] = rsqrtf(var + LN_EPS);
  }
  __syncthreads();
  const float mean = stat[0], rs = stat[1];
  const int j = tid;
  const float iv = (combL[j]          - mean) * rs * gamma[j]          + beta[j];
  const float fv = (combL[NO + j]     - mean) * rs * gamma[NO + j]     + beta[NO + j];
  const float gv = (combL[2 * NO + j] - mean) * rs * gamma[2 * NO + j] + beta[2 * NO + j];
  const float ov = (combL[3 * NO + j] - mean) * rs * gamma[3 * NO + j] + beta[3 * NO + j];
  const float cold = cst[(size_t)m * NO + j];
  const float cc = sigf(fv) * cold + sigf(iv) * tanhfast(gv);
  const float hh = sigf(ov) * cc;
  cst[(size_t)m * NO + j] = cc;
  out[((size_t)m * NS + t) * NO + j] = hh;
  hfrag[hfrag_idx(m, j)] = __float2bfloat16(hh);
}

// ---------------- fallback (small ws): fp32 path ----------------

__launch_bounds__(256)
__global__ void step_gemm_f32(const float* __restrict__ x, const float* __restrict__ hf,
                              const float* __restrict__ W, const float* __restrict__ bias,
                              float* __restrict__ comb, int t) {
  const int blk = blockIdx.x;
  const int tid = threadIdx.x;
  const int n   = blk * 16 + (tid & 15);
  const int mlo = tid >> 4;
  float a0 = 0.f, a1 = 0.f;
  for (int k = 0; k < NI; ++k) {
    const float wv = W[(size_t)k * NC + n];
    a0 += x[((size_t)mlo * NS + t) * NI + k] * wv;
    a1 += x[((size_t)(mlo + 16) * NS + t) * NI + k] * wv;
  }
  for (int k = 0; k < NO; ++k) {
    const float wv = W[(size_t)(NI + k) * NC + n];
    a0 += hf[mlo * NO + k] * wv;
    a1 += hf[(mlo + 16) * NO + k] * wv;
  }
  comb[(size_t)mlo * NC + n] = a0 + bias[n];
  comb[(size_t)(mlo + 16) * NC + n] = a1 + bias[n];
}

__global__ __launch_bounds__(1024)
void step_update_row_f32(const float* __restrict__ comb,
                         const float* __restrict__ gamma,
                         const float* __restrict__ beta,
                         float* __restrict__ cst,
                         float* __restrict__ out,
                         float* __restrict__ hf,
                         int t) {
  __shared__ __align__(16) float combL[NC];
  __shared__ float red[16][2];
  __shared__ float stat[2];
  const int m = blockIdx.x, tid = threadIdx.x;
  f32x4 cv = *(const f32x4*)(comb + (size_t)m * NC + tid * 4);
  *(f32x4*)(combL + tid * 4) = cv;
  float s  = cv[0] + cv[1] + cv[2] + cv[3];
  float ss = cv[0] * cv[0] + cv[1] * cv[1] + cv[2] * cv[2] + cv[3] * cv[3];
#pragma unroll
  for (int off = 1; off < 64; off <<= 1) {
    s  += __shfl_xor(s, off);
    ss += __shfl_xor(ss, off);
  }
  const int wid = tid >> 6;
  if ((tid & 63) == 0) { red[wid][0] = s; red[wid][1] = ss; }
  __syncthreads();
  if (tid == 0) {
    float s2 = 0.f, ss2 = 0.f;
    for (int i = 0; i < 16; ++i) { s2 += red[i][0]; ss2 += red[i][1]; }
    const float mean = s2 * (1.f / NC);
    const float var  = ss2 * (1.f / NC) - mean * mean;
    stat[0] = mean;
    stat[1] = rsqrtf(var + LN_EPS);
  }
  __syncthreads();
  const float mean = stat[0], rs = stat[1];
  const int j = tid;
  const float iv = (combL[j]          - mean) * rs * gamma[j]          + beta[j];
  const float fv = (combL[NO + j]     - mean) * rs * gamma[NO + j]     + beta[NO + j];
  const float gv = (combL[2 * NO + j] - mean) * rs * gamma[2 * NO + j] + beta[2 * NO + j];
  const float ov = (combL[3 * NO + j] - mean) * rs * gamma[3 * NO + j] + beta[3 * NO + j];
  const float cold = cst[(size_t)m * NO + j];
  const float cc = sigf(fv) * cold + sigf(iv) * tanhfast(gv);
  const float hh = sigf(ov) * cc;
  cst[(size_t)m * NO + j] = cc;
  out[((size_t)m * NS + t) * NO + j] = hh;
  hf[(size_t)m * NO + j] = hh;
}

// ---------------- launch ----------------

extern "C" void kernel_launch(void* const* d_in, const int* in_sizes, int n_in,
                              void* d_out, int out_size, void* d_ws, size_t ws_size,
                              hipStream_t stream) {
  (void)in_sizes; (void)n_in; (void)out_size;
  const float* x     = (const float*)d_in[0];
  const float* W     = (const float*)d_in[1];
  const float* bias  = (const float*)d_in[2];
  const float* gamma = (const float*)d_in[3];
  const float* beta  = (const float*)d_in[4];
  const float* hx0   = (const float*)d_in[5];
  const float* cx0   = (const float*)d_in[6];
  float* outp = (float*)d_out;

  char* ws = (char*)d_ws;
  size_t off = 0;
  auto alloc = [&](size_t bytes) -> char* {
    off = (off + 255) & ~(size_t)255;
    char* p = ws + off;
    off += bytes;
    return p;
  };
  // small buffers first (fallback needs only comb/cst/hf)
  float* comb           = (float*)alloc((size_t)NB * NC * 4);            // 512KB
  float* cst            = (float*)alloc((size_t)NB * NO * 4);            // 128KB
  float* hf             = (float*)alloc((size_t)NB * NO * 4);            // 128KB
  __hip_bfloat16* hfrag = (__hip_bfloat16*)alloc((size_t)NB * NO * 2);   // 64KB
  // mid buffers (tier2 = exact round-0 path)
  __hip_bfloat16* xfrag = (__hip_bfloat16*)alloc((size_t)NB * NS * NI * 2);  // 16.8MB
  __hip_bfloat16* WF    = (__hip_bfloat16*)alloc((size_t)NK * NC * 2);       // 16.8MB
  const size_t off_tier2 = off;
  // big buffer (tier1 = hoisted-x path): xa bf16 [t][block][tid]
  __hip_bfloat16* xa    = (__hip_bfloat16*)alloc((size_t)NS * NB * NC * 2);  // 67MB
  const size_t off_tier1 = off;

  const bool tier1 = (ws_size >= off_tier1);  // ws_size constant -> same path every call
  const bool tier2 = (ws_size >= off_tier2);

  if (tier1) {
    hipLaunchKernelGGL(init_state, dim3((NB * NO) / 256), dim3(256), 0, stream,
                       hx0, cx0, hfrag, cst, hf);
    hipLaunchKernelGGL(pack_x, dim3(NS, 32), dim3(128), 0, stream, x, xfrag);
    hipLaunchKernelGGL(pack_wf, dim3(256 * 64), dim3(64), 0, stream, W, WF);
    hipLaunchKernelGGL(xgemm_all, dim3(256), dim3(512), 0, stream,
                       xfrag, WF, bias, xa);
    for (int t = 0; t < NS; ++t) {
      hipLaunchKernelGGL(step_gemm_h, dim3(256), dim3(512), 0, stream,
                         hfrag, WF, xa, comb, t);
      hipLaunchKernelGGL(step_update_row, dim3(NB), dim3(1024), 0, stream,
                         comb, gamma, beta, cst, outp, hfrag, t);
    }
  } else if (tier2) {
    hipLaunchKernelGGL(init_state, dim3((NB * NO) / 256), dim3(256), 0, stream,
                       hx0, cx0, hfrag, cst, hf);
    hipLaunchKernelGGL(pack_x, dim3(NS, 32), dim3(128), 0, stream, x, xfrag);
    hipLaunchKernelGGL(pack_wf, dim3(256 * 64), dim3(64), 0, stream, W, WF);
    for (int t = 0; t < NS; ++t) {
      hipLaunchKernelGGL(step_gemm_mfma, dim3(256), dim3(512), 0, stream,
                         xfrag, hfrag, WF, bias, comb, t);
      hipLaunchKernelGGL(step_update_row, dim3(NB), dim3(1024), 0, stream,
                         comb, gamma, beta, cst, outp, hfrag, t);
    }
  } else {
    hipLaunchKernelGGL(init_state, dim3((NB * NO) / 256), dim3(256), 0, stream,
                       hx0, cx0, hfrag, cst, hf);
    for (int t = 0; t < NS; ++t) {
      hipLaunchKernelGGL(step_gemm_f32, dim3(256), dim3(256), 0, stream,
                         x, hf, W, bias, comb, t);
      hipLaunchKernelGGL(step_update_row_f32, dim3(NB), dim3(1024), 0, stream,
                         comb, gamma, beta, cst, outp, hf, t);
    }
  }
}